// Round 1
// baseline (1732.733 us; speedup 1.0000x reference)
//
#include <hip/hip_runtime.h>
#include <math.h>

#define NN 100000
#define EE 1200000

__device__ __forceinline__ float leakyf(float x, float s) {
    return x >= 0.f ? x : s * x;
}

// atomic float max via int/uint monotonicity trick (no NaNs in this workload)
__device__ __forceinline__ void atomicMaxF(float* addr, float val) {
    if (val >= 0.f) atomicMax((int*)addr, __float_as_int(val));
    else            atomicMin((unsigned int*)addr, __float_as_uint(val));
}

// C = A[N,64] @ W[64,64], optionally (+bias, leaky slope), optionally per-row
// dot products with att_src/att_dst (a_s, a_d).  16 rows per 256-thread block.
template<bool BIAS_LEAKY, bool ATT>
__global__ void lin64_kernel(const float* __restrict__ A,
                             const float* __restrict__ W,
                             const float* __restrict__ bias,
                             const float* __restrict__ att_src,
                             const float* __restrict__ att_dst,
                             float* __restrict__ out,
                             float* __restrict__ a_s,
                             float* __restrict__ a_d,
                             float slope) {
    __shared__ float Wl[64][64];   // Wl[k][c] : lanes read consecutive c -> 2-way (free)
    __shared__ float Al[16][64];   // Al[r][k] : broadcast
    const int tid  = threadIdx.x;
    const int row0 = blockIdx.x * 16;

    for (int i = tid; i < 4096; i += 256) Wl[i >> 6][i & 63] = W[i];
    for (int i = tid; i < 1024; i += 256) Al[i >> 6][i & 63] = A[row0 * 64 + i];
    __syncthreads();

    const int cg = tid >> 6;      // wave id: rows r = cg, cg+4, cg+8, cg+12
    const int c  = tid & 63;      // output column == lane
    for (int r = cg; r < 16; r += 4) {
        float acc = 0.f;
        #pragma unroll
        for (int k = 0; k < 64; ++k)
            acc = fmaf(Al[r][k], Wl[k][c], acc);
        if (BIAS_LEAKY) acc = leakyf(acc + bias[c], slope);
        out[(row0 + r) * 64 + c] = acc;
        if (ATT) {
            float ps = acc * att_src[c];
            float pd = acc * att_dst[c];
            #pragma unroll
            for (int off = 32; off > 0; off >>= 1) {
                ps += __shfl_down(ps, off);
                pd += __shfl_down(pd, off);
            }
            if (c == 0) { a_s[row0 + r] = ps; a_d[row0 + r] = pd; }
        }
    }
}

// out[N,64] = (A0[N,64] ++ A1[N,64]) @ W2[128,64] + b2
__global__ void final_kernel(const float* __restrict__ A0,
                             const float* __restrict__ A1,
                             const float* __restrict__ W2,
                             const float* __restrict__ b2,
                             float* __restrict__ out) {
    __shared__ float Wl[128][64];
    __shared__ float Al[16][128];
    const int tid  = threadIdx.x;
    const int row0 = blockIdx.x * 16;

    for (int i = tid; i < 8192; i += 256) Wl[i >> 6][i & 63] = W2[i];
    for (int i = tid; i < 1024; i += 256) {
        int r = i >> 6, k = i & 63;
        Al[r][k]      = A0[(row0 + r) * 64 + k];
        Al[r][64 + k] = A1[(row0 + r) * 64 + k];
    }
    __syncthreads();

    const int cg = tid >> 6, c = tid & 63;
    for (int r = cg; r < 16; r += 4) {
        float acc = b2[c];
        #pragma unroll
        for (int k = 0; k < 128; ++k)
            acc = fmaf(Al[r][k], Wl[k][c], acc);
        out[(row0 + r) * 64 + c] = acc;
    }
}

// m = -inf, denom = 0, out[n][c] = bias[c]
__global__ void init_nodes(float* __restrict__ m, float* __restrict__ denom,
                           float* __restrict__ out, const float* __restrict__ bias) {
    int i = blockIdx.x * blockDim.x + threadIdx.x;
    if (i >= NN * 64) return;
    out[i] = bias[i & 63];
    if (i < NN) { m[i] = __uint_as_float(0xff800000u); denom[i] = 0.f; }
}

// pass 1: per-dst segment max of leaky(a_s[src]+a_d[dst], 0.2); self loops at [E, E+N)
__global__ void edge_max(const int* __restrict__ src, const int* __restrict__ dst,
                         const float* __restrict__ a_s, const float* __restrict__ a_d,
                         float* __restrict__ m) {
    int e = blockIdx.x * blockDim.x + threadIdx.x;
    if (e >= EE + NN) return;
    int s = (e < EE) ? src[e] : (e - EE);
    int d = (e < EE) ? dst[e] : (e - EE);
    float v = leakyf(a_s[s] + a_d[d], 0.2f);
    atomicMaxF(&m[d], v);
}

// pass 2: denom[dst] += exp(e - m[dst])
__global__ void edge_denom(const int* __restrict__ src, const int* __restrict__ dst,
                           const float* __restrict__ a_s, const float* __restrict__ a_d,
                           const float* __restrict__ m, float* __restrict__ denom) {
    int e = blockIdx.x * blockDim.x + threadIdx.x;
    if (e >= EE + NN) return;
    int s = (e < EE) ? src[e] : (e - EE);
    int d = (e < EE) ? dst[e] : (e - EE);
    float v = leakyf(a_s[s] + a_d[d], 0.2f);
    atomicAdd(&denom[d], expf(v - m[d]));
}

// pass 3: out[dst] += alpha * hW[src]  (one wave per edge, lane == channel)
__global__ void edge_scatter(const int* __restrict__ src, const int* __restrict__ dst,
                             const float* __restrict__ a_s, const float* __restrict__ a_d,
                             const float* __restrict__ m, const float* __restrict__ denom,
                             const float* __restrict__ hW, float* __restrict__ out) {
    long long t = (long long)blockIdx.x * blockDim.x + threadIdx.x;
    int e    = (int)(t >> 6);
    int lane = (int)(t & 63);
    if (e >= EE + NN) return;
    int s = (e < EE) ? src[e] : (e - EE);
    int d = (e < EE) ? dst[e] : (e - EE);
    float v     = leakyf(a_s[s] + a_d[d], 0.2f);
    float alpha = expf(v - m[d]) / (denom[d] + 1e-16f);
    atomicAdd(&out[d * 64 + lane], alpha * hW[s * 64 + lane]);
}

extern "C" void kernel_launch(void* const* d_in, const int* in_sizes, int n_in,
                              void* d_out, int out_size, void* d_ws, size_t ws_size,
                              hipStream_t stream) {
    const float* x      = (const float*)d_in[0];
    const int*   ei     = (const int*)  d_in[1];   // [2,E]: src = ei, dst = ei+E
    const float* rg_x   = (const float*)d_in[3];
    const int*   rei    = (const int*)  d_in[4];
    const float* W1     = (const float*)d_in[6];
    const float* b1     = (const float*)d_in[7];
    const float* atom_W  = (const float*)d_in[8];
    const float* atom_as = (const float*)d_in[9];
    const float* atom_ad = (const float*)d_in[10];
    const float* atom_b  = (const float*)d_in[11];
    const float* rg_W    = (const float*)d_in[12];
    const float* rg_as   = (const float*)d_in[13];
    const float* rg_ad   = (const float*)d_in[14];
    const float* rg_b    = (const float*)d_in[15];
    const float* mol_W   = (const float*)d_in[16];
    const float* mol_as  = (const float*)d_in[17];
    const float* mol_ad  = (const float*)d_in[18];
    const float* mol_b   = (const float*)d_in[19];
    const float* W2     = (const float*)d_in[20];
    const float* b2     = (const float*)d_in[21];

    float* ws   = (float*)d_ws;
    float* A    = ws;                 // 6.4M floats
    float* B    = A + (size_t)NN * 64;
    float* Cb   = B + (size_t)NN * 64;
    float* D    = Cb + (size_t)NN * 64;
    float* a_s  = D + (size_t)NN * 64;
    float* a_d  = a_s + NN;
    float* m    = a_d + NN;
    float* den  = m + NN;

    const int EN = EE + NN;
    const dim3 blk(256);
    const int gRows  = NN / 16;                 // 6250 (exact)
    const int gNode  = (NN * 64 + 255) / 256;
    const int gEdge  = (EN + 255) / 256;
    const int gScat  = (int)(((long long)EN * 64 + 255) / 256);

    // one full GATConv: Hin --(W,att)--> HW,a_s,a_d ; edge softmax-scatter -> Hout
    auto conv = [&](const float* Hin, const int* edges, const float* Wc,
                    const float* asv, const float* adv, const float* bias,
                    float* HW, float* Hout) {
        lin64_kernel<false, true><<<gRows, blk, 0, stream>>>(
            Hin, Wc, nullptr, asv, adv, HW, a_s, a_d, 0.f);
        init_nodes<<<gNode, blk, 0, stream>>>(m, den, Hout, bias);
        edge_max<<<gEdge, blk, 0, stream>>>(edges, edges + EE, a_s, a_d, m);
        edge_denom<<<gEdge, blk, 0, stream>>>(edges, edges + EE, a_s, a_d, m, den);
        edge_scatter<<<gScat, blk, 0, stream>>>(edges, edges + EE, a_s, a_d, m, den, HW, Hout);
    };

    // h0 = leaky(x@W1+b1, .01) -> A
    lin64_kernel<true, false><<<gRows, blk, 0, stream>>>(
        x, W1, b1, nullptr, nullptr, A, nullptr, nullptr, 0.01f);
    // atom conv: A -> Cb (HW in B)
    conv(A, ei, atom_W, atom_as, atom_ad, atom_b, B, Cb);
    // rh0 = leaky(rg_x@W1+b1, .01) -> A (h0 no longer needed)
    lin64_kernel<true, false><<<gRows, blk, 0, stream>>>(
        rg_x, W1, b1, nullptr, nullptr, A, nullptr, nullptr, 0.01f);
    // rg conv: A -> D (HW in B)
    conv(A, rei, rg_W, rg_as, rg_ad, rg_b, B, D);
    // mol conv: Cb -> A (HW in B; A free after rg pre-pass consumed it)
    conv(Cb, ei, mol_W, mol_as, mol_ad, mol_b, B, A);
    // out = [A ++ D] @ W2 + b2
    final_kernel<<<gRows, blk, 0, stream>>>(A, D, W2, b2, (float*)d_out);
}

// Round 2
// 1527.345 us; speedup vs baseline: 1.1345x; 1.1345x over previous
//
#include <hip/hip_runtime.h>
#include <math.h>

#define NN 100000
#define EE 1200000
#define SCAN_B 256
#define NBLK ((NN + SCAN_B - 1) / SCAN_B)   // 391

__device__ __forceinline__ float leakyf(float x, float s) {
    return x >= 0.f ? x : s * x;
}

// ---------------- CSR build ----------------

__global__ void count_deg(const int* __restrict__ dst, int* __restrict__ deg) {
    int e = blockIdx.x * 256 + threadIdx.x;
    if (e < EE) atomicAdd(&deg[dst[e]], 1);
}

__global__ void scan_local(const int* __restrict__ deg, int* __restrict__ excl,
                           int* __restrict__ bsum) {
    __shared__ int tmp[SCAN_B];
    int tid = threadIdx.x;
    int i = blockIdx.x * SCAN_B + tid;
    int v = (i < NN) ? deg[i] : 0;
    tmp[tid] = v;
    __syncthreads();
    for (int off = 1; off < SCAN_B; off <<= 1) {
        int t = (tid >= off) ? tmp[tid - off] : 0;
        __syncthreads();
        tmp[tid] += t;
        __syncthreads();
    }
    if (i < NN) excl[i] = tmp[tid] - v;
    if (tid == SCAN_B - 1) bsum[blockIdx.x] = tmp[tid];
}

__global__ void scan_bsum(int* __restrict__ bsum, int nb) {
    __shared__ int tmp[SCAN_B];
    __shared__ int carry;
    int tid = threadIdx.x;
    if (tid == 0) carry = 0;
    __syncthreads();
    for (int base = 0; base < nb; base += SCAN_B) {
        int v = (base + tid < nb) ? bsum[base + tid] : 0;
        tmp[tid] = v;
        __syncthreads();
        for (int off = 1; off < SCAN_B; off <<= 1) {
            int t = (tid >= off) ? tmp[tid - off] : 0;
            __syncthreads();
            tmp[tid] += t;
            __syncthreads();
        }
        int c = carry;
        if (base + tid < nb) bsum[base + tid] = c + tmp[tid] - v;  // exclusive
        __syncthreads();
        if (tid == 0) carry = c + tmp[SCAN_B - 1];
        __syncthreads();
    }
}

__global__ void finalize_rows(const int* __restrict__ excl, const int* __restrict__ bsum,
                              int* __restrict__ rowstart, int* __restrict__ cursor) {
    int i = blockIdx.x * 256 + threadIdx.x;
    if (i < NN) {
        int r = excl[i] + bsum[i >> 8];
        rowstart[i] = r;
        cursor[i] = r;
    }
    if (i == NN) rowstart[NN] = EE;
}

__global__ void fill_csr(const int* __restrict__ src, const int* __restrict__ dst,
                         int* __restrict__ cursor, int* __restrict__ col) {
    int e = blockIdx.x * 256 + threadIdx.x;
    if (e < EE) {
        int p = atomicAdd(&cursor[dst[e]], 1);
        col[p] = src[e];
    }
}

// ---------------- GEMM building blocks (64x64 tile, thread = 4 rows x 4 cols) ----------------

__device__ __forceinline__ void load_w(const float* __restrict__ W, float (*__restrict__ L)[64],
                                       int tid) {
    #pragma unroll
    for (int j = 0; j < 4; ++j) {
        int idx = tid + j * 256;          // float4 index 0..1023
        *(float4*)&L[idx >> 4][(idx & 15) * 4] = *(const float4*)&W[idx * 4];
    }
}

__device__ __forceinline__ void load_tile(const float* __restrict__ G, int row0,
                                          float (*__restrict__ L)[64], int tid) {
    #pragma unroll
    for (int j = 0; j < 4; ++j) {
        int idx = tid + j * 256;
        int r = idx >> 4, c4 = idx & 15;
        int row = row0 + r;
        float4 v = make_float4(0.f, 0.f, 0.f, 0.f);
        if (row < NN) v = *(const float4*)&G[(size_t)row * 64 + c4 * 4];
        *(float4*)&L[r][c4 * 4] = v;
    }
}

// acc[i] (rows r0..r0+3, cols 4q..4q+3) += Al-rows @ Wl
__device__ __forceinline__ void mm64(const float (*__restrict__ Al)[64],
                                     const float (*__restrict__ Wl)[64],
                                     int r0, int q, float4* acc) {
    #pragma unroll
    for (int k0 = 0; k0 < 64; k0 += 4) {
        float4 w0 = *(const float4*)&Wl[k0 + 0][q * 4];
        float4 w1 = *(const float4*)&Wl[k0 + 1][q * 4];
        float4 w2 = *(const float4*)&Wl[k0 + 2][q * 4];
        float4 w3 = *(const float4*)&Wl[k0 + 3][q * 4];
        #pragma unroll
        for (int i = 0; i < 4; ++i) {
            float4 a = *(const float4*)&Al[r0 + i][k0];
            acc[i].x = fmaf(a.x, w0.x, acc[i].x); acc[i].x = fmaf(a.y, w1.x, acc[i].x);
            acc[i].x = fmaf(a.z, w2.x, acc[i].x); acc[i].x = fmaf(a.w, w3.x, acc[i].x);
            acc[i].y = fmaf(a.x, w0.y, acc[i].y); acc[i].y = fmaf(a.y, w1.y, acc[i].y);
            acc[i].y = fmaf(a.z, w2.y, acc[i].y); acc[i].y = fmaf(a.w, w3.y, acc[i].y);
            acc[i].z = fmaf(a.x, w0.z, acc[i].z); acc[i].z = fmaf(a.y, w1.z, acc[i].z);
            acc[i].z = fmaf(a.z, w2.z, acc[i].z); acc[i].z = fmaf(a.w, w3.z, acc[i].z);
            acc[i].w = fmaf(a.x, w0.w, acc[i].w); acc[i].w = fmaf(a.y, w1.w, acc[i].w);
            acc[i].w = fmaf(a.z, w2.w, acc[i].w); acc[i].w = fmaf(a.w, w3.w, acc[i].w);
        }
    }
}

__device__ __forceinline__ void att_epilogue(const float4* acc, int row0, int r0, int q, int tid,
                                             const float* __restrict__ att_s,
                                             const float* __restrict__ att_d,
                                             float* __restrict__ hW,
                                             float* __restrict__ a_s,
                                             float* __restrict__ a_d) {
    float4 as4 = *(const float4*)&att_s[q * 4];
    float4 ad4 = *(const float4*)&att_d[q * 4];
    #pragma unroll
    for (int i = 0; i < 4; ++i) {
        int row = row0 + r0 + i;
        if (row < NN) *(float4*)&hW[(size_t)row * 64 + q * 4] = acc[i];
        float ps = acc[i].x * as4.x + acc[i].y * as4.y + acc[i].z * as4.z + acc[i].w * as4.w;
        float pd = acc[i].x * ad4.x + acc[i].y * ad4.y + acc[i].z * ad4.z + acc[i].w * ad4.w;
        #pragma unroll
        for (int off = 1; off < 16; off <<= 1) {
            ps += __shfl_xor(ps, off);
            pd += __shfl_xor(pd, off);
        }
        if ((tid & 15) == 0 && row < NN) { a_s[row] = ps; a_d[row] = pd; }
    }
}

// fused: h = leaky(x@W1+b1, .01); hW = h@Wc; a_s/a_d row dots
__global__ __launch_bounds__(256) void lin1_pre_gat(
        const float* __restrict__ x, const float* __restrict__ W1, const float* __restrict__ b1,
        const float* __restrict__ Wc, const float* __restrict__ att_s, const float* __restrict__ att_d,
        float* __restrict__ hW, float* __restrict__ a_s, float* __restrict__ a_d) {
    __shared__ float Al[64][64];
    __shared__ float W1l[64][64];
    __shared__ float Wcl[64][64];
    const int tid = threadIdx.x, row0 = blockIdx.x * 64;
    load_w(W1, W1l, tid);
    load_w(Wc, Wcl, tid);
    load_tile(x, row0, Al, tid);
    __syncthreads();
    const int r0 = (tid >> 4) * 4, q = tid & 15;
    float4 acc[4] = {{0,0,0,0},{0,0,0,0},{0,0,0,0},{0,0,0,0}};
    mm64(Al, W1l, r0, q, acc);
    __syncthreads();   // all reads of Al done; reuse as H tile
    float4 bb = *(const float4*)&b1[q * 4];
    #pragma unroll
    for (int i = 0; i < 4; ++i) {
        float4 h;
        h.x = leakyf(acc[i].x + bb.x, 0.01f);
        h.y = leakyf(acc[i].y + bb.y, 0.01f);
        h.z = leakyf(acc[i].z + bb.z, 0.01f);
        h.w = leakyf(acc[i].w + bb.w, 0.01f);
        *(float4*)&Al[r0 + i][q * 4] = h;
        acc[i] = make_float4(0.f, 0.f, 0.f, 0.f);
    }
    __syncthreads();
    mm64(Al, Wcl, r0, q, acc);
    att_epilogue(acc, row0, r0, q, tid, att_s, att_d, hW, a_s, a_d);
}

// hW = H@Wc; a_s/a_d row dots
__global__ __launch_bounds__(256) void pre_gat(
        const float* __restrict__ H, const float* __restrict__ Wc,
        const float* __restrict__ att_s, const float* __restrict__ att_d,
        float* __restrict__ hW, float* __restrict__ a_s, float* __restrict__ a_d) {
    __shared__ float Al[64][64];
    __shared__ float Wcl[64][64];
    const int tid = threadIdx.x, row0 = blockIdx.x * 64;
    load_w(Wc, Wcl, tid);
    load_tile(H, row0, Al, tid);
    __syncthreads();
    const int r0 = (tid >> 4) * 4, q = tid & 15;
    float4 acc[4] = {{0,0,0,0},{0,0,0,0},{0,0,0,0},{0,0,0,0}};
    mm64(Al, Wcl, r0, q, acc);
    att_epilogue(acc, row0, r0, q, tid, att_s, att_d, hW, a_s, a_d);
}

// out = [A0 ++ A1] @ W2 + b2
__global__ __launch_bounds__(256) void final_gemm(
        const float* __restrict__ A0, const float* __restrict__ A1,
        const float* __restrict__ W2, const float* __restrict__ b2, float* __restrict__ out) {
    __shared__ float Al[64][64];
    __shared__ float W2a[64][64];
    __shared__ float W2b[64][64];
    const int tid = threadIdx.x, row0 = blockIdx.x * 64;
    load_w(W2, W2a, tid);
    load_w(W2 + 4096, W2b, tid);
    load_tile(A0, row0, Al, tid);
    __syncthreads();
    const int r0 = (tid >> 4) * 4, q = tid & 15;
    float4 bb = *(const float4*)&b2[q * 4];
    float4 acc[4] = {bb, bb, bb, bb};
    mm64(Al, W2a, r0, q, acc);
    __syncthreads();
    load_tile(A1, row0, Al, tid);
    __syncthreads();
    mm64(Al, W2b, r0, q, acc);
    #pragma unroll
    for (int i = 0; i < 4; ++i) {
        int row = row0 + r0 + i;
        if (row < NN) *(float4*)&out[(size_t)row * 64 + q * 4] = acc[i];
    }
}

// ---------------- fused segment-softmax aggregate (gather, no atomics) ----------------
// one wave per dst node; lane == channel
__global__ __launch_bounds__(256) void aggregate(
        const int* __restrict__ rowstart, const int* __restrict__ col,
        const float* __restrict__ a_s, const float* __restrict__ a_d,
        const float* __restrict__ hW, const float* __restrict__ bias,
        float* __restrict__ out) {
    const int wave = threadIdx.x >> 6, lane = threadIdx.x & 63;
    const int d = blockIdx.x * 4 + wave;
    if (d >= NN) return;
    const int start = rowstart[d], end = rowstart[d + 1];
    const float ad = a_d[d];
    const float vself = leakyf(a_s[d] + ad, 0.2f);

    // pass 1: max (lane-strided), cache first 64 edges' (s, v) in lane registers
    int s_l = 0;
    float v_l = -1e30f;
    int j0 = start + lane;
    if (j0 < end) {
        s_l = col[j0];
        v_l = leakyf(a_s[s_l] + ad, 0.2f);
    }
    float mx = fmaxf(vself, v_l);
    for (int j = j0 + 64; j < end; j += 64)
        mx = fmaxf(mx, leakyf(a_s[col[j]] + ad, 0.2f));
    #pragma unroll
    for (int off = 32; off; off >>= 1) mx = fmaxf(mx, __shfl_xor(mx, off));

    // pass 2: exp-weighted accumulate (self loop + edges), normalize at the end
    float den = __expf(vself - mx);
    float acc = den * hW[(size_t)d * 64 + lane];
    const int deg = end - start;
    const int n0 = deg < 64 ? deg : 64;
    for (int idx = 0; idx < n0; ++idx) {
        int s = __shfl(s_l, idx);
        float v = __shfl(v_l, idx);
        float ex = __expf(v - mx);
        den += ex;
        acc = fmaf(ex, hW[(size_t)s * 64 + lane], acc);
    }
    for (int j = start + 64; j < end; ++j) {   // rare (deg > 64)
        int s = col[j];
        float ex = __expf(leakyf(a_s[s] + ad, 0.2f) - mx);
        den += ex;
        acc = fmaf(ex, hW[(size_t)s * 64 + lane], acc);
    }
    out[(size_t)d * 64 + lane] = acc / (den + 1e-16f) + bias[lane];
}

// ---------------- launch ----------------

extern "C" void kernel_launch(void* const* d_in, const int* in_sizes, int n_in,
                              void* d_out, int out_size, void* d_ws, size_t ws_size,
                              hipStream_t stream) {
    const float* x      = (const float*)d_in[0];
    const int*   ei     = (const int*)  d_in[1];   // src = ei, dst = ei + EE
    const float* rg_x   = (const float*)d_in[3];
    const int*   rei    = (const int*)  d_in[4];
    const float* W1     = (const float*)d_in[6];
    const float* b1     = (const float*)d_in[7];
    const float* atom_W  = (const float*)d_in[8];
    const float* atom_as = (const float*)d_in[9];
    const float* atom_ad = (const float*)d_in[10];
    const float* atom_b  = (const float*)d_in[11];
    const float* rg_W    = (const float*)d_in[12];
    const float* rg_as   = (const float*)d_in[13];
    const float* rg_ad   = (const float*)d_in[14];
    const float* rg_b    = (const float*)d_in[15];
    const float* mol_W   = (const float*)d_in[16];
    const float* mol_as  = (const float*)d_in[17];
    const float* mol_ad  = (const float*)d_in[18];
    const float* mol_b   = (const float*)d_in[19];
    const float* W2     = (const float*)d_in[20];
    const float* b2     = (const float*)d_in[21];

    // workspace layout
    float* fp   = (float*)d_ws;
    float* hW   = fp;                       fp += (size_t)NN * 64;
    float* bufX = fp;                       fp += (size_t)NN * 64;   // atom out -> mol out
    float* rgO  = fp;                       fp += (size_t)NN * 64;
    float* a_s  = fp;                       fp += NN;
    float* a_d  = fp;                       fp += NN;
    int* ip = (int*)fp;
    int* deg1 = ip;            ip += NN;
    int* excl1 = ip;           ip += NN;
    int* bsum1 = ip;           ip += NBLK;
    int* row1 = ip;            ip += NN + 1;
    int* cur1 = ip;            ip += NN;
    int* col1 = ip;            ip += EE;
    int* deg2 = ip;            ip += NN;
    int* excl2 = ip;           ip += NN;
    int* bsum2 = ip;           ip += NBLK;
    int* row2 = ip;            ip += NN + 1;
    int* cur2 = ip;            ip += NN;
    int* col2 = ip;            ip += EE;

    const dim3 blk(256);
    const int gE   = (EE + 255) / 256;
    const int gN1  = (NN + 256) / 256;        // covers NN inclusive
    const int gT   = (NN + 63) / 64;          // 64-row GEMM tiles
    const int gAgg = (NN + 3) / 4;

    hipMemsetAsync(deg1, 0, (size_t)NN * 4, stream);
    hipMemsetAsync(deg2, 0, (size_t)NN * 4, stream);

    // CSR for atom graph (used by atom & mol convs) and rg graph
    count_deg<<<gE, blk, 0, stream>>>(ei + EE, deg1);
    count_deg<<<gE, blk, 0, stream>>>(rei + EE, deg2);
    scan_local<<<NBLK, blk, 0, stream>>>(deg1, excl1, bsum1);
    scan_local<<<NBLK, blk, 0, stream>>>(deg2, excl2, bsum2);
    scan_bsum<<<1, blk, 0, stream>>>(bsum1, NBLK);
    scan_bsum<<<1, blk, 0, stream>>>(bsum2, NBLK);
    finalize_rows<<<gN1, blk, 0, stream>>>(excl1, bsum1, row1, cur1);
    finalize_rows<<<gN1, blk, 0, stream>>>(excl2, bsum2, row2, cur2);
    fill_csr<<<gE, blk, 0, stream>>>(ei, ei + EE, cur1, col1);
    fill_csr<<<gE, blk, 0, stream>>>(rei, rei + EE, cur2, col2);

    // atom conv (fused lin1)
    lin1_pre_gat<<<gT, blk, 0, stream>>>(x, W1, b1, atom_W, atom_as, atom_ad, hW, a_s, a_d);
    aggregate<<<gAgg, blk, 0, stream>>>(row1, col1, a_s, a_d, hW, atom_b, bufX);
    // rg conv (fused lin1)
    lin1_pre_gat<<<gT, blk, 0, stream>>>(rg_x, W1, b1, rg_W, rg_as, rg_ad, hW, a_s, a_d);
    aggregate<<<gAgg, blk, 0, stream>>>(row2, col2, a_s, a_d, hW, rg_b, rgO);
    // mol conv on atom output
    pre_gat<<<gT, blk, 0, stream>>>(bufX, mol_W, mol_as, mol_ad, hW, a_s, a_d);
    aggregate<<<gAgg, blk, 0, stream>>>(row1, col1, a_s, a_d, hW, mol_b, bufX);
    // final concat GEMM
    final_gemm<<<gT, blk, 0, stream>>>(bufX, rgO, W2, b2, (float*)d_out);
}

// Round 3
// 849.845 us; speedup vs baseline: 2.0389x; 1.7972x over previous
//
#include <hip/hip_runtime.h>
#include <math.h>

#define NN 100000
#define EE 1200000
#define SCAN_B 256
#define NBLK ((NN + SCAN_B - 1) / SCAN_B)   // 391

__device__ __forceinline__ float leakyf(float x, float s) {
    return x >= 0.f ? x : s * x;
}

// ---------------- CSR build ----------------

__global__ void count_deg(const int* __restrict__ dst, int* __restrict__ deg) {
    int e = blockIdx.x * 256 + threadIdx.x;
    if (e < EE) atomicAdd(&deg[dst[e]], 1);
}

__global__ void scan_local(const int* __restrict__ deg, int* __restrict__ excl,
                           int* __restrict__ bsum) {
    __shared__ int tmp[SCAN_B];
    int tid = threadIdx.x;
    int i = blockIdx.x * SCAN_B + tid;
    int v = (i < NN) ? deg[i] : 0;
    tmp[tid] = v;
    __syncthreads();
    for (int off = 1; off < SCAN_B; off <<= 1) {
        int t = (tid >= off) ? tmp[tid - off] : 0;
        __syncthreads();
        tmp[tid] += t;
        __syncthreads();
    }
    if (i < NN) excl[i] = tmp[tid] - v;
    if (tid == SCAN_B - 1) bsum[blockIdx.x] = tmp[tid];
}

__global__ void scan_bsum(int* __restrict__ bsum, int nb) {
    __shared__ int tmp[SCAN_B];
    __shared__ int carry;
    int tid = threadIdx.x;
    if (tid == 0) carry = 0;
    __syncthreads();
    for (int base = 0; base < nb; base += SCAN_B) {
        int v = (base + tid < nb) ? bsum[base + tid] : 0;
        tmp[tid] = v;
        __syncthreads();
        for (int off = 1; off < SCAN_B; off <<= 1) {
            int t = (tid >= off) ? tmp[tid - off] : 0;
            __syncthreads();
            tmp[tid] += t;
            __syncthreads();
        }
        int c = carry;
        if (base + tid < nb) bsum[base + tid] = c + tmp[tid] - v;  // exclusive
        __syncthreads();
        if (tid == 0) carry = c + tmp[SCAN_B - 1];
        __syncthreads();
    }
}

__global__ void finalize_rows(const int* __restrict__ excl, const int* __restrict__ bsum,
                              int* __restrict__ rowstart, int* __restrict__ cursor) {
    int i = blockIdx.x * 256 + threadIdx.x;
    if (i < NN) {
        int r = excl[i] + bsum[i >> 8];
        rowstart[i] = r;
        cursor[i] = r;
    }
    if (i == NN) rowstart[NN] = EE;
}

__global__ void fill_csr(const int* __restrict__ src, const int* __restrict__ dst,
                         int* __restrict__ cursor, int* __restrict__ col) {
    int e = blockIdx.x * 256 + threadIdx.x;
    if (e < EE) {
        int p = atomicAdd(&cursor[dst[e]], 1);
        col[p] = src[e];
    }
}

// ---------------- GEMM building blocks (64x64 tile, thread = 4 rows x 4 cols) ----------------

__device__ __forceinline__ void load_w(const float* __restrict__ W, float (*__restrict__ L)[64],
                                       int tid) {
    #pragma unroll
    for (int j = 0; j < 4; ++j) {
        int idx = tid + j * 256;          // float4 index 0..1023
        *(float4*)&L[idx >> 4][(idx & 15) * 4] = *(const float4*)&W[idx * 4];
    }
}

__device__ __forceinline__ void load_tile(const float* __restrict__ G, int row0,
                                          float (*__restrict__ L)[64], int tid) {
    #pragma unroll
    for (int j = 0; j < 4; ++j) {
        int idx = tid + j * 256;
        int r = idx >> 4, c4 = idx & 15;
        int row = row0 + r;
        float4 v = make_float4(0.f, 0.f, 0.f, 0.f);
        if (row < NN) v = *(const float4*)&G[(size_t)row * 64 + c4 * 4];
        *(float4*)&L[r][c4 * 4] = v;
    }
}

// acc[i] (rows r0..r0+3, cols 4q..4q+3) += Al-rows @ Wl
// NOTE: unroll 2 (not full) — full unroll software-pipelines 16 iterations of
// LDS loads, blows the VGPR budget (R2: 256 VGPR + 1.6 GB scratch spill traffic).
__device__ __forceinline__ void mm64(const float (*__restrict__ Al)[64],
                                     const float (*__restrict__ Wl)[64],
                                     int r0, int q, float4* acc) {
    #pragma unroll 2
    for (int k0 = 0; k0 < 64; k0 += 4) {
        float4 w0 = *(const float4*)&Wl[k0 + 0][q * 4];
        float4 w1 = *(const float4*)&Wl[k0 + 1][q * 4];
        float4 w2 = *(const float4*)&Wl[k0 + 2][q * 4];
        float4 w3 = *(const float4*)&Wl[k0 + 3][q * 4];
        #pragma unroll
        for (int i = 0; i < 4; ++i) {
            float4 a = *(const float4*)&Al[r0 + i][k0];
            acc[i].x = fmaf(a.x, w0.x, acc[i].x); acc[i].x = fmaf(a.y, w1.x, acc[i].x);
            acc[i].x = fmaf(a.z, w2.x, acc[i].x); acc[i].x = fmaf(a.w, w3.x, acc[i].x);
            acc[i].y = fmaf(a.x, w0.y, acc[i].y); acc[i].y = fmaf(a.y, w1.y, acc[i].y);
            acc[i].y = fmaf(a.z, w2.y, acc[i].y); acc[i].y = fmaf(a.w, w3.y, acc[i].y);
            acc[i].z = fmaf(a.x, w0.z, acc[i].z); acc[i].z = fmaf(a.y, w1.z, acc[i].z);
            acc[i].z = fmaf(a.z, w2.z, acc[i].z); acc[i].z = fmaf(a.w, w3.z, acc[i].z);
            acc[i].w = fmaf(a.x, w0.w, acc[i].w); acc[i].w = fmaf(a.y, w1.w, acc[i].w);
            acc[i].w = fmaf(a.z, w2.w, acc[i].w); acc[i].w = fmaf(a.w, w3.w, acc[i].w);
        }
    }
}

__device__ __forceinline__ void att_epilogue(const float4* acc, int row0, int r0, int q, int tid,
                                             const float* __restrict__ att_s,
                                             const float* __restrict__ att_d,
                                             float* __restrict__ hW,
                                             float* __restrict__ a_s,
                                             float* __restrict__ a_d) {
    float4 as4 = *(const float4*)&att_s[q * 4];
    float4 ad4 = *(const float4*)&att_d[q * 4];
    #pragma unroll
    for (int i = 0; i < 4; ++i) {
        int row = row0 + r0 + i;
        if (row < NN) *(float4*)&hW[(size_t)row * 64 + q * 4] = acc[i];
        float ps = acc[i].x * as4.x + acc[i].y * as4.y + acc[i].z * as4.z + acc[i].w * as4.w;
        float pd = acc[i].x * ad4.x + acc[i].y * ad4.y + acc[i].z * ad4.z + acc[i].w * ad4.w;
        #pragma unroll
        for (int off = 1; off < 16; off <<= 1) {
            ps += __shfl_xor(ps, off);
            pd += __shfl_xor(pd, off);
        }
        if ((tid & 15) == 0 && row < NN) { a_s[row] = ps; a_d[row] = pd; }
    }
}

// fused: h = leaky(x@W1+b1, .01); hW = h@Wc; a_s/a_d row dots.
// Single time-shared W buffer: LDS 32KB, VGPR capped at 128 (anti-spill).
__global__ __launch_bounds__(256, 4) void lin1_pre_gat(
        const float* __restrict__ x, const float* __restrict__ W1, const float* __restrict__ b1,
        const float* __restrict__ Wc, const float* __restrict__ att_s, const float* __restrict__ att_d,
        float* __restrict__ hW, float* __restrict__ a_s, float* __restrict__ a_d) {
    __shared__ float Al[64][64];
    __shared__ float Wl[64][64];
    const int tid = threadIdx.x, row0 = blockIdx.x * 64;
    load_w(W1, Wl, tid);
    load_tile(x, row0, Al, tid);
    __syncthreads();
    const int r0 = (tid >> 4) * 4, q = tid & 15;
    float4 acc[4] = {{0,0,0,0},{0,0,0,0},{0,0,0,0},{0,0,0,0}};
    mm64(Al, Wl, r0, q, acc);
    __syncthreads();   // all reads of Al/Wl done; reuse Al as H tile, Wl for Wc
    load_w(Wc, Wl, tid);
    float4 bb = *(const float4*)&b1[q * 4];
    #pragma unroll
    for (int i = 0; i < 4; ++i) {
        float4 h;
        h.x = leakyf(acc[i].x + bb.x, 0.01f);
        h.y = leakyf(acc[i].y + bb.y, 0.01f);
        h.z = leakyf(acc[i].z + bb.z, 0.01f);
        h.w = leakyf(acc[i].w + bb.w, 0.01f);
        *(float4*)&Al[r0 + i][q * 4] = h;
        acc[i] = make_float4(0.f, 0.f, 0.f, 0.f);
    }
    __syncthreads();
    mm64(Al, Wl, r0, q, acc);
    att_epilogue(acc, row0, r0, q, tid, att_s, att_d, hW, a_s, a_d);
}

// hW = H@Wc; a_s/a_d row dots
__global__ __launch_bounds__(256, 4) void pre_gat(
        const float* __restrict__ H, const float* __restrict__ Wc,
        const float* __restrict__ att_s, const float* __restrict__ att_d,
        float* __restrict__ hW, float* __restrict__ a_s, float* __restrict__ a_d) {
    __shared__ float Al[64][64];
    __shared__ float Wcl[64][64];
    const int tid = threadIdx.x, row0 = blockIdx.x * 64;
    load_w(Wc, Wcl, tid);
    load_tile(H, row0, Al, tid);
    __syncthreads();
    const int r0 = (tid >> 4) * 4, q = tid & 15;
    float4 acc[4] = {{0,0,0,0},{0,0,0,0},{0,0,0,0},{0,0,0,0}};
    mm64(Al, Wcl, r0, q, acc);
    att_epilogue(acc, row0, r0, q, tid, att_s, att_d, hW, a_s, a_d);
}

// out = [A0 ++ A1] @ W2 + b2  (time-shared W buffer: 32KB LDS, two halves)
__global__ __launch_bounds__(256, 4) void final_gemm(
        const float* __restrict__ A0, const float* __restrict__ A1,
        const float* __restrict__ W2, const float* __restrict__ b2, float* __restrict__ out) {
    __shared__ float Al[64][64];
    __shared__ float Wl[64][64];
    const int tid = threadIdx.x, row0 = blockIdx.x * 64;
    load_w(W2, Wl, tid);
    load_tile(A0, row0, Al, tid);
    __syncthreads();
    const int r0 = (tid >> 4) * 4, q = tid & 15;
    float4 bb = *(const float4*)&b2[q * 4];
    float4 acc[4] = {bb, bb, bb, bb};
    mm64(Al, Wl, r0, q, acc);
    __syncthreads();
    load_w(W2 + 4096, Wl, tid);
    load_tile(A1, row0, Al, tid);
    __syncthreads();
    mm64(Al, Wl, r0, q, acc);
    #pragma unroll
    for (int i = 0; i < 4; ++i) {
        int row = row0 + r0 + i;
        if (row < NN) *(float4*)&out[(size_t)row * 64 + q * 4] = acc[i];
    }
}

// ---------------- fused segment-softmax aggregate (gather, no atomics) ----------------
// one wave per dst node; lane == channel
__global__ __launch_bounds__(256) void aggregate(
        const int* __restrict__ rowstart, const int* __restrict__ col,
        const float* __restrict__ a_s, const float* __restrict__ a_d,
        const float* __restrict__ hW, const float* __restrict__ bias,
        float* __restrict__ out) {
    const int wave = threadIdx.x >> 6, lane = threadIdx.x & 63;
    const int d = blockIdx.x * 4 + wave;
    if (d >= NN) return;
    const int start = rowstart[d], end = rowstart[d + 1];
    const float ad = a_d[d];
    const float vself = leakyf(a_s[d] + ad, 0.2f);

    // pass 1: max (lane-strided), cache first 64 edges' (s, v) in lane registers
    int s_l = 0;
    float v_l = -1e30f;
    int j0 = start + lane;
    if (j0 < end) {
        s_l = col[j0];
        v_l = leakyf(a_s[s_l] + ad, 0.2f);
    }
    float mx = fmaxf(vself, v_l);
    for (int j = j0 + 64; j < end; j += 64)
        mx = fmaxf(mx, leakyf(a_s[col[j]] + ad, 0.2f));
    #pragma unroll
    for (int off = 32; off; off >>= 1) mx = fmaxf(mx, __shfl_xor(mx, off));

    // pass 2: exp-weighted accumulate (self loop + edges), normalize at the end
    float den = __expf(vself - mx);
    float acc = den * hW[(size_t)d * 64 + lane];
    const int deg = end - start;
    const int n0 = deg < 64 ? deg : 64;
    for (int idx = 0; idx < n0; ++idx) {
        int s = __shfl(s_l, idx);
        float v = __shfl(v_l, idx);
        float ex = __expf(v - mx);
        den += ex;
        acc = fmaf(ex, hW[(size_t)s * 64 + lane], acc);
    }
    for (int j = start + 64; j < end; ++j) {   // rare (deg > 64)
        int s = col[j];
        float ex = __expf(leakyf(a_s[s] + ad, 0.2f) - mx);
        den += ex;
        acc = fmaf(ex, hW[(size_t)s * 64 + lane], acc);
    }
    out[(size_t)d * 64 + lane] = acc / (den + 1e-16f) + bias[lane];
}

// ---------------- launch ----------------

extern "C" void kernel_launch(void* const* d_in, const int* in_sizes, int n_in,
                              void* d_out, int out_size, void* d_ws, size_t ws_size,
                              hipStream_t stream) {
    const float* x      = (const float*)d_in[0];
    const int*   ei     = (const int*)  d_in[1];   // src = ei, dst = ei + EE
    const float* rg_x   = (const float*)d_in[3];
    const int*   rei    = (const int*)  d_in[4];
    const float* W1     = (const float*)d_in[6];
    const float* b1     = (const float*)d_in[7];
    const float* atom_W  = (const float*)d_in[8];
    const float* atom_as = (const float*)d_in[9];
    const float* atom_ad = (const float*)d_in[10];
    const float* atom_b  = (const float*)d_in[11];
    const float* rg_W    = (const float*)d_in[12];
    const float* rg_as   = (const float*)d_in[13];
    const float* rg_ad   = (const float*)d_in[14];
    const float* rg_b    = (const float*)d_in[15];
    const float* mol_W   = (const float*)d_in[16];
    const float* mol_as  = (const float*)d_in[17];
    const float* mol_ad  = (const float*)d_in[18];
    const float* mol_b   = (const float*)d_in[19];
    const float* W2     = (const float*)d_in[20];
    const float* b2     = (const float*)d_in[21];

    // workspace layout
    float* fp   = (float*)d_ws;
    float* hW   = fp;                       fp += (size_t)NN * 64;
    float* bufX = fp;                       fp += (size_t)NN * 64;   // atom out -> mol out
    float* rgO  = fp;                       fp += (size_t)NN * 64;
    float* a_s  = fp;                       fp += NN;
    float* a_d  = fp;                       fp += NN;
    int* ip = (int*)fp;
    int* deg1 = ip;            ip += NN;
    int* excl1 = ip;           ip += NN;
    int* bsum1 = ip;           ip += NBLK;
    int* row1 = ip;            ip += NN + 1;
    int* cur1 = ip;            ip += NN;
    int* col1 = ip;            ip += EE;
    int* deg2 = ip;            ip += NN;
    int* excl2 = ip;           ip += NN;
    int* bsum2 = ip;           ip += NBLK;
    int* row2 = ip;            ip += NN + 1;
    int* cur2 = ip;            ip += NN;
    int* col2 = ip;            ip += EE;

    const dim3 blk(256);
    const int gE   = (EE + 255) / 256;
    const int gN1  = (NN + 256) / 256;        // covers NN inclusive
    const int gT   = (NN + 63) / 64;          // 64-row GEMM tiles
    const int gAgg = (NN + 3) / 4;

    hipMemsetAsync(deg1, 0, (size_t)NN * 4, stream);
    hipMemsetAsync(deg2, 0, (size_t)NN * 4, stream);

    // CSR for atom graph (used by atom & mol convs) and rg graph
    count_deg<<<gE, blk, 0, stream>>>(ei + EE, deg1);
    count_deg<<<gE, blk, 0, stream>>>(rei + EE, deg2);
    scan_local<<<NBLK, blk, 0, stream>>>(deg1, excl1, bsum1);
    scan_local<<<NBLK, blk, 0, stream>>>(deg2, excl2, bsum2);
    scan_bsum<<<1, blk, 0, stream>>>(bsum1, NBLK);
    scan_bsum<<<1, blk, 0, stream>>>(bsum2, NBLK);
    finalize_rows<<<gN1, blk, 0, stream>>>(excl1, bsum1, row1, cur1);
    finalize_rows<<<gN1, blk, 0, stream>>>(excl2, bsum2, row2, cur2);
    fill_csr<<<gE, blk, 0, stream>>>(ei, ei + EE, cur1, col1);
    fill_csr<<<gE, blk, 0, stream>>>(rei, rei + EE, cur2, col2);

    // atom conv (fused lin1)
    lin1_pre_gat<<<gT, blk, 0, stream>>>(x, W1, b1, atom_W, atom_as, atom_ad, hW, a_s, a_d);
    aggregate<<<gAgg, blk, 0, stream>>>(row1, col1, a_s, a_d, hW, atom_b, bufX);
    // rg conv (fused lin1)
    lin1_pre_gat<<<gT, blk, 0, stream>>>(rg_x, W1, b1, rg_W, rg_as, rg_ad, hW, a_s, a_d);
    aggregate<<<gAgg, blk, 0, stream>>>(row2, col2, a_s, a_d, hW, rg_b, rgO);
    // mol conv on atom output
    pre_gat<<<gT, blk, 0, stream>>>(bufX, mol_W, mol_as, mol_ad, hW, a_s, a_d);
    aggregate<<<gAgg, blk, 0, stream>>>(row1, col1, a_s, a_d, hW, mol_b, bufX);
    // final concat GEMM
    final_gemm<<<gT, blk, 0, stream>>>(bufX, rgO, W2, b2, (float*)d_out);
}

// Round 4
// 652.327 us; speedup vs baseline: 2.6562x; 1.3028x over previous
//
#include <hip/hip_runtime.h>
#include <hip/hip_fp16.h>
#include <math.h>

#define NN 100000
#define EE 1200000
#define SCAN_B 256
#define NBLK ((NN + SCAN_B - 1) / SCAN_B)   // 391

__device__ __forceinline__ float leakyf(float x, float s) {
    return x >= 0.f ? x : s * x;
}

// ---------------- CSR build (both graphs per launch) ----------------

// rank[e] = arrival index of edge e within its dst segment (the atomic we pay anyway)
__global__ void count_rank(const int* __restrict__ dst1, const int* __restrict__ dst2,
                           int* __restrict__ deg1, int* __restrict__ deg2,
                           int* __restrict__ rank1, int* __restrict__ rank2) {
    int e = blockIdx.x * 256 + threadIdx.x;
    if (e < EE) {
        rank1[e] = atomicAdd(&deg1[dst1[e]], 1);
    } else {
        int i = e - EE;                     // grid is exactly 2*EE threads
        rank2[i] = atomicAdd(&deg2[dst2[i]], 1);
    }
}

__global__ void scan_local2(const int* __restrict__ deg1, const int* __restrict__ deg2,
                            int* __restrict__ excl1, int* __restrict__ excl2,
                            int* __restrict__ bsum1, int* __restrict__ bsum2) {
    __shared__ int tmp[SCAN_B];
    const int b = blockIdx.x;
    const int* deg  = (b < NBLK) ? deg1  : deg2;
    int* excl       = (b < NBLK) ? excl1 : excl2;
    int* bsum       = (b < NBLK) ? bsum1 : bsum2;
    const int blk   = (b < NBLK) ? b : b - NBLK;
    int tid = threadIdx.x;
    int i = blk * SCAN_B + tid;
    int v = (i < NN) ? deg[i] : 0;
    tmp[tid] = v;
    __syncthreads();
    for (int off = 1; off < SCAN_B; off <<= 1) {
        int t = (tid >= off) ? tmp[tid - off] : 0;
        __syncthreads();
        tmp[tid] += t;
        __syncthreads();
    }
    if (i < NN) excl[i] = tmp[tid] - v;
    if (tid == SCAN_B - 1) bsum[blk] = tmp[tid];
}

__global__ void scan_bsum2(int* __restrict__ bsum1, int* __restrict__ bsum2) {
    __shared__ int tmp[SCAN_B];
    __shared__ int carry;
    int* bsum = (blockIdx.x == 0) ? bsum1 : bsum2;
    int tid = threadIdx.x;
    if (tid == 0) carry = 0;
    __syncthreads();
    for (int base = 0; base < NBLK; base += SCAN_B) {
        int v = (base + tid < NBLK) ? bsum[base + tid] : 0;
        tmp[tid] = v;
        __syncthreads();
        for (int off = 1; off < SCAN_B; off <<= 1) {
            int t = (tid >= off) ? tmp[tid - off] : 0;
            __syncthreads();
            tmp[tid] += t;
            __syncthreads();
        }
        int c = carry;
        if (base + tid < NBLK) bsum[base + tid] = c + tmp[tid] - v;  // exclusive
        __syncthreads();
        if (tid == 0) carry = c + tmp[SCAN_B - 1];
        __syncthreads();
    }
}

__global__ void finalize2(const int* __restrict__ excl1, const int* __restrict__ bsum1,
                          int* __restrict__ row1,
                          const int* __restrict__ excl2, const int* __restrict__ bsum2,
                          int* __restrict__ row2) {
    int i = blockIdx.x * 256 + threadIdx.x;
    if (i < NN) {
        row1[i] = excl1[i] + bsum1[i >> 8];
        row2[i] = excl2[i] + bsum2[i >> 8];
    } else if (i == NN) {
        row1[NN] = EE;
        row2[NN] = EE;
    }
}

// atomic-free fill: position = row[dst] + rank  (row[] is L2-resident, 400KB)
__global__ void fill2(const int* __restrict__ ei, const int* __restrict__ rei,
                      const int* __restrict__ rank1, const int* __restrict__ rank2,
                      const int* __restrict__ row1, const int* __restrict__ row2,
                      int* __restrict__ col1, int* __restrict__ col2) {
    int e = blockIdx.x * 256 + threadIdx.x;
    if (e < EE) {
        col1[row1[ei[EE + e]] + rank1[e]] = ei[e];
    } else {
        int i = e - EE;
        col2[row2[rei[EE + i]] + rank2[i]] = rei[i];
    }
}

// ---------------- GEMM building blocks (64x64 tile, thread = 4 rows x 4 cols) ----------------

__device__ __forceinline__ void load_w(const float* __restrict__ W, float (*__restrict__ L)[64],
                                       int tid) {
    #pragma unroll
    for (int j = 0; j < 4; ++j) {
        int idx = tid + j * 256;          // float4 index 0..1023
        *(float4*)&L[idx >> 4][(idx & 15) * 4] = *(const float4*)&W[idx * 4];
    }
}

__device__ __forceinline__ void load_tile(const float* __restrict__ G, int row0,
                                          float (*__restrict__ L)[64], int tid) {
    #pragma unroll
    for (int j = 0; j < 4; ++j) {
        int idx = tid + j * 256;
        int r = idx >> 4, c4 = idx & 15;
        int row = row0 + r;
        float4 v = make_float4(0.f, 0.f, 0.f, 0.f);
        if (row < NN) v = *(const float4*)&G[(size_t)row * 64 + c4 * 4];
        *(float4*)&L[r][c4 * 4] = v;
    }
}

// acc[i] (rows r0..r0+3, cols 4q..4q+3) += Al-rows @ Wl
// unroll 2 only: full unroll blew VGPR budget (R2: 256 VGPR + 1.6GB spill traffic)
__device__ __forceinline__ void mm64(const float (*__restrict__ Al)[64],
                                     const float (*__restrict__ Wl)[64],
                                     int r0, int q, float4* acc) {
    #pragma unroll 2
    for (int k0 = 0; k0 < 64; k0 += 4) {
        float4 w0 = *(const float4*)&Wl[k0 + 0][q * 4];
        float4 w1 = *(const float4*)&Wl[k0 + 1][q * 4];
        float4 w2 = *(const float4*)&Wl[k0 + 2][q * 4];
        float4 w3 = *(const float4*)&Wl[k0 + 3][q * 4];
        #pragma unroll
        for (int i = 0; i < 4; ++i) {
            float4 a = *(const float4*)&Al[r0 + i][k0];
            acc[i].x = fmaf(a.x, w0.x, acc[i].x); acc[i].x = fmaf(a.y, w1.x, acc[i].x);
            acc[i].x = fmaf(a.z, w2.x, acc[i].x); acc[i].x = fmaf(a.w, w3.x, acc[i].x);
            acc[i].y = fmaf(a.x, w0.y, acc[i].y); acc[i].y = fmaf(a.y, w1.y, acc[i].y);
            acc[i].y = fmaf(a.z, w2.y, acc[i].y); acc[i].y = fmaf(a.w, w3.y, acc[i].y);
            acc[i].z = fmaf(a.x, w0.z, acc[i].z); acc[i].z = fmaf(a.y, w1.z, acc[i].z);
            acc[i].z = fmaf(a.z, w2.z, acc[i].z); acc[i].z = fmaf(a.w, w3.z, acc[i].z);
            acc[i].w = fmaf(a.x, w0.w, acc[i].w); acc[i].w = fmaf(a.y, w1.w, acc[i].w);
            acc[i].w = fmaf(a.z, w2.w, acc[i].w); acc[i].w = fmaf(a.w, w3.w, acc[i].w);
        }
    }
}

// epilogue: store hW as fp16 (halves gather traffic in aggregate), a_s/a_d row dots
__device__ __forceinline__ void att_epilogue(const float4* acc, int row0, int r0, int q, int tid,
                                             const float* __restrict__ att_s,
                                             const float* __restrict__ att_d,
                                             __half* __restrict__ hW,
                                             float* __restrict__ a_s,
                                             float* __restrict__ a_d) {
    float4 as4 = *(const float4*)&att_s[q * 4];
    float4 ad4 = *(const float4*)&att_d[q * 4];
    #pragma unroll
    for (int i = 0; i < 4; ++i) {
        int row = row0 + r0 + i;
        if (row < NN) {
            union { float2 f2; __half2 h2[2]; } u;
            u.h2[0] = __floats2half2_rn(acc[i].x, acc[i].y);
            u.h2[1] = __floats2half2_rn(acc[i].z, acc[i].w);
            *(float2*)&hW[(size_t)row * 64 + q * 4] = u.f2;
        }
        float ps = acc[i].x * as4.x + acc[i].y * as4.y + acc[i].z * as4.z + acc[i].w * as4.w;
        float pd = acc[i].x * ad4.x + acc[i].y * ad4.y + acc[i].z * ad4.z + acc[i].w * ad4.w;
        #pragma unroll
        for (int off = 1; off < 16; off <<= 1) {
            ps += __shfl_xor(ps, off);
            pd += __shfl_xor(pd, off);
        }
        if ((tid & 15) == 0 && row < NN) { a_s[row] = ps; a_d[row] = pd; }
    }
}

// fused: h = leaky(x@W1+b1, .01); hW = h@Wc; a_s/a_d row dots
__global__ __launch_bounds__(256, 4) void lin1_pre_gat(
        const float* __restrict__ x, const float* __restrict__ W1, const float* __restrict__ b1,
        const float* __restrict__ Wc, const float* __restrict__ att_s, const float* __restrict__ att_d,
        __half* __restrict__ hW, float* __restrict__ a_s, float* __restrict__ a_d) {
    __shared__ float Al[64][64];
    __shared__ float Wl[64][64];
    const int tid = threadIdx.x, row0 = blockIdx.x * 64;
    load_w(W1, Wl, tid);
    load_tile(x, row0, Al, tid);
    __syncthreads();
    const int r0 = (tid >> 4) * 4, q = tid & 15;
    float4 acc[4] = {{0,0,0,0},{0,0,0,0},{0,0,0,0},{0,0,0,0}};
    mm64(Al, Wl, r0, q, acc);
    __syncthreads();   // reads of Al/Wl done; reuse Al as H tile, Wl for Wc
    load_w(Wc, Wl, tid);
    float4 bb = *(const float4*)&b1[q * 4];
    #pragma unroll
    for (int i = 0; i < 4; ++i) {
        float4 h;
        h.x = leakyf(acc[i].x + bb.x, 0.01f);
        h.y = leakyf(acc[i].y + bb.y, 0.01f);
        h.z = leakyf(acc[i].z + bb.z, 0.01f);
        h.w = leakyf(acc[i].w + bb.w, 0.01f);
        *(float4*)&Al[r0 + i][q * 4] = h;
        acc[i] = make_float4(0.f, 0.f, 0.f, 0.f);
    }
    __syncthreads();
    mm64(Al, Wl, r0, q, acc);
    att_epilogue(acc, row0, r0, q, tid, att_s, att_d, hW, a_s, a_d);
}

// hW = H@Wc; a_s/a_d row dots
__global__ __launch_bounds__(256, 4) void pre_gat(
        const float* __restrict__ H, const float* __restrict__ Wc,
        const float* __restrict__ att_s, const float* __restrict__ att_d,
        __half* __restrict__ hW, float* __restrict__ a_s, float* __restrict__ a_d) {
    __shared__ float Al[64][64];
    __shared__ float Wcl[64][64];
    const int tid = threadIdx.x, row0 = blockIdx.x * 64;
    load_w(Wc, Wcl, tid);
    load_tile(H, row0, Al, tid);
    __syncthreads();
    const int r0 = (tid >> 4) * 4, q = tid & 15;
    float4 acc[4] = {{0,0,0,0},{0,0,0,0},{0,0,0,0},{0,0,0,0}};
    mm64(Al, Wcl, r0, q, acc);
    att_epilogue(acc, row0, r0, q, tid, att_s, att_d, hW, a_s, a_d);
}

// out = [A0 ++ A1] @ W2 + b2  (time-shared W buffer)
__global__ __launch_bounds__(256, 4) void final_gemm(
        const float* __restrict__ A0, const float* __restrict__ A1,
        const float* __restrict__ W2, const float* __restrict__ b2, float* __restrict__ out) {
    __shared__ float Al[64][64];
    __shared__ float Wl[64][64];
    const int tid = threadIdx.x, row0 = blockIdx.x * 64;
    load_w(W2, Wl, tid);
    load_tile(A0, row0, Al, tid);
    __syncthreads();
    const int r0 = (tid >> 4) * 4, q = tid & 15;
    float4 bb = *(const float4*)&b2[q * 4];
    float4 acc[4] = {bb, bb, bb, bb};
    mm64(Al, Wl, r0, q, acc);
    __syncthreads();
    load_w(W2 + 4096, Wl, tid);
    load_tile(A1, row0, Al, tid);
    __syncthreads();
    mm64(Al, Wl, r0, q, acc);
    #pragma unroll
    for (int i = 0; i < 4; ++i) {
        int row = row0 + r0 + i;
        if (row < NN) *(float4*)&out[(size_t)row * 64 + q * 4] = acc[i];
    }
}

// ---------------- fused segment-softmax aggregate (gather, no atomics) ----------------
// one wave per dst node; lane == channel; exp hoisted out of inner loop
// (each lane computes ex for ITS cached edge once; inner loop is shfl+load+fma)
__global__ __launch_bounds__(256) void aggregate(
        const int* __restrict__ rowstart, const int* __restrict__ col,
        const float* __restrict__ a_s, const float* __restrict__ a_d,
        const __half* __restrict__ hW, const float* __restrict__ bias,
        float* __restrict__ out) {
    const int wave = threadIdx.x >> 6, lane = threadIdx.x & 63;
    const int d = blockIdx.x * 4 + wave;
    if (d >= NN) return;
    const int start = rowstart[d], end = rowstart[d + 1];
    const float ad = a_d[d];
    const float vself = leakyf(a_s[d] + ad, 0.2f);

    // pass 1: cache first-64 edges' (s, v) in lane registers; strided tail for deg>64
    int s_l = 0;
    float v_l = -1e30f;
    int j0 = start + lane;
    if (j0 < end) {
        s_l = col[j0];
        v_l = leakyf(a_s[s_l] + ad, 0.2f);
    }
    float mx = fmaxf(vself, v_l);
    for (int j = j0 + 64; j < end; j += 64)
        mx = fmaxf(mx, leakyf(a_s[col[j]] + ad, 0.2f));
    #pragma unroll
    for (int off = 32; off; off >>= 1) mx = fmaxf(mx, __shfl_xor(mx, off));

    // per-lane exp once; den via butterfly reduce
    float ex_l = (j0 < end) ? __expf(v_l - mx) : 0.f;
    float den = ex_l;
    #pragma unroll
    for (int off = 32; off; off >>= 1) den += __shfl_xor(den, off);
    float exself = __expf(vself - mx);
    den += exself;
    float acc = exself * __half2float(hW[(size_t)d * 64 + lane]);

    const int deg = end - start;
    const int n0 = deg < 64 ? deg : 64;
    int idx = 0;
    for (; idx + 4 <= n0; idx += 4) {       // 4-wide: 4 independent row loads in flight
        int   s0 = __shfl(s_l, idx),     s1 = __shfl(s_l, idx + 1);
        int   s2 = __shfl(s_l, idx + 2), s3 = __shfl(s_l, idx + 3);
        float e0 = __shfl(ex_l, idx),     e1 = __shfl(ex_l, idx + 1);
        float e2 = __shfl(ex_l, idx + 2), e3 = __shfl(ex_l, idx + 3);
        float r0v = __half2float(hW[(size_t)s0 * 64 + lane]);
        float r1v = __half2float(hW[(size_t)s1 * 64 + lane]);
        float r2v = __half2float(hW[(size_t)s2 * 64 + lane]);
        float r3v = __half2float(hW[(size_t)s3 * 64 + lane]);
        acc = fmaf(e0, r0v, acc); acc = fmaf(e1, r1v, acc);
        acc = fmaf(e2, r2v, acc); acc = fmaf(e3, r3v, acc);
    }
    for (; idx < n0; ++idx) {
        int   s = __shfl(s_l, idx);
        float e = __shfl(ex_l, idx);
        acc = fmaf(e, __half2float(hW[(size_t)s * 64 + lane]), acc);
    }
    for (int j = start + 64; j < end; ++j) {   // rare tail (deg > 64)
        int s = col[j];
        float ex = __expf(leakyf(a_s[s] + ad, 0.2f) - mx);
        den += ex;
        acc = fmaf(ex, __half2float(hW[(size_t)s * 64 + lane]), acc);
    }
    out[(size_t)d * 64 + lane] = acc / (den + 1e-16f) + bias[lane];
}

// ---------------- launch ----------------

extern "C" void kernel_launch(void* const* d_in, const int* in_sizes, int n_in,
                              void* d_out, int out_size, void* d_ws, size_t ws_size,
                              hipStream_t stream) {
    const float* x      = (const float*)d_in[0];
    const int*   ei     = (const int*)  d_in[1];   // src = ei, dst = ei + EE
    const float* rg_x   = (const float*)d_in[3];
    const int*   rei    = (const int*)  d_in[4];
    const float* W1     = (const float*)d_in[6];
    const float* b1     = (const float*)d_in[7];
    const float* atom_W  = (const float*)d_in[8];
    const float* atom_as = (const float*)d_in[9];
    const float* atom_ad = (const float*)d_in[10];
    const float* atom_b  = (const float*)d_in[11];
    const float* rg_W    = (const float*)d_in[12];
    const float* rg_as   = (const float*)d_in[13];
    const float* rg_ad   = (const float*)d_in[14];
    const float* rg_b    = (const float*)d_in[15];
    const float* mol_W   = (const float*)d_in[16];
    const float* mol_as  = (const float*)d_in[17];
    const float* mol_ad  = (const float*)d_in[18];
    const float* mol_b   = (const float*)d_in[19];
    const float* W2     = (const float*)d_in[20];
    const float* b2     = (const float*)d_in[21];

    // workspace layout
    float* fp   = (float*)d_ws;
    float* bufX = fp;                       fp += (size_t)NN * 64;   // atom out -> mol out
    float* rgO  = fp;                       fp += (size_t)NN * 64;
    float* a_s  = fp;                       fp += NN;
    float* a_d  = fp;                       fp += NN;
    __half* hW  = (__half*)fp;              fp += (size_t)NN * 32;   // NN*64 halves
    int* ip = (int*)fp;
    int* deg1  = ip;           ip += NN;    // deg1/deg2 contiguous: single memset
    int* deg2  = ip;           ip += NN;
    int* rank1 = ip;           ip += EE;
    int* rank2 = ip;           ip += EE;
    int* excl1 = ip;           ip += NN;
    int* excl2 = ip;           ip += NN;
    int* bsum1 = ip;           ip += NBLK;
    int* bsum2 = ip;           ip += NBLK;
    int* row1  = ip;           ip += NN + 1;
    int* row2  = ip;           ip += NN + 1;
    int* col1  = ip;           ip += EE;
    int* col2  = ip;           ip += EE;

    const dim3 blk(256);
    const int gE2  = (2 * EE + 255) / 256;      // 9375 (exactly 2*EE threads)
    const int gN1  = (NN + 256) / 256;          // covers NN inclusive
    const int gT   = (NN + 63) / 64;            // 64-row GEMM tiles
    const int gAgg = (NN + 3) / 4;

    hipMemsetAsync(deg1, 0, (size_t)2 * NN * 4, stream);

    // CSR for atom graph (used by atom & mol convs) and rg graph — both per launch
    count_rank<<<gE2, blk, 0, stream>>>(ei + EE, rei + EE, deg1, deg2, rank1, rank2);
    scan_local2<<<2 * NBLK, blk, 0, stream>>>(deg1, deg2, excl1, excl2, bsum1, bsum2);
    scan_bsum2<<<2, blk, 0, stream>>>(bsum1, bsum2);
    finalize2<<<gN1, blk, 0, stream>>>(excl1, bsum1, row1, excl2, bsum2, row2);
    fill2<<<gE2, blk, 0, stream>>>(ei, rei, rank1, rank2, row1, row2, col1, col2);

    // atom conv (fused lin1)
    lin1_pre_gat<<<gT, blk, 0, stream>>>(x, W1, b1, atom_W, atom_as, atom_ad, hW, a_s, a_d);
    aggregate<<<gAgg, blk, 0, stream>>>(row1, col1, a_s, a_d, hW, atom_b, bufX);
    // rg conv (fused lin1)
    lin1_pre_gat<<<gT, blk, 0, stream>>>(rg_x, W1, b1, rg_W, rg_as, rg_ad, hW, a_s, a_d);
    aggregate<<<gAgg, blk, 0, stream>>>(row2, col2, a_s, a_d, hW, rg_b, rgO);
    // mol conv on atom output
    pre_gat<<<gT, blk, 0, stream>>>(bufX, mol_W, mol_as, mol_ad, hW, a_s, a_d);
    aggregate<<<gAgg, blk, 0, stream>>>(row1, col1, a_s, a_d, hW, mol_b, bufX);
    // final concat GEMM
    final_gemm<<<gT, blk, 0, stream>>>(bufX, rgO, W2, b2, (float*)d_out);
}